// Round 13
// baseline (56.652 us; speedup 1.0000x reference)
//
#include <hip/hip_runtime.h>

// Problem constants (from reference)
#define BATCH   4
#define N_VERTS 10000
#define N_FACES 20000
#define CUT_NUM 8
#define N_SAMP  80000
#define CC      128
#define NXCD    8

typedef float          f32x4 __attribute__((ext_vector_type(4)));
typedef int            i32x4 __attribute__((ext_vector_type(4)));
typedef unsigned short u16x8 __attribute__((ext_vector_type(8)));

#define N_E        (N_VERTS * CUT_NUM)                          // 80000
#define XB16_BYTES ((size_t)BATCH * N_VERTS * CC * 2)           // 10.24 MB
#define QUAD_BYTES ((size_t)N_E * sizeof(i32x4))                // 1.28 MB
#define WREC_BYTES ((size_t)N_E * BATCH * sizeof(f32x4))        // 5.12 MB
#define CONV_BLOCKS 2500   // 2500*256*8 == BATCH*N_VERTS*CC exactly
#define IDX_BLOCKS  313    // ceil(80000/256)
#define WREC_BLOCKS 1250   // 320000/256 exactly

__device__ inline float bf16_to_f32(unsigned short u) {
    return __uint_as_float((unsigned)u << 16);
}

// round-to-nearest-even f32 -> bf16
__device__ inline unsigned short f32_to_bf16(float f) {
    unsigned u = __float_as_uint(f);
    unsigned rounding = 0x7fffu + ((u >> 16) & 1u);
    return (unsigned short)((u + rounding) >> 16);
}

// ---------------------------------------------------------------------------
// Fused prep, 3 segments:
//  [0, CONV)            : x_features f32 -> bf16 table
//  [CONV, CONV+IDX)     : quad[e] = {F[I[s]][0..2], s}, s = xg[e]
//  [CONV+IDX, +WREC)    : wrec[e*4+b] = {Bw[b][xg[e]][0..2], 0} (random gather
//                         moved out of the main kernel; coalesced 16B writes)
// ---------------------------------------------------------------------------
__global__ __launch_bounds__(256) void prep_kernel(
    const float* __restrict__ xf,
    const float* __restrict__ Bw,
    const int*   __restrict__ xg,
    const int*   __restrict__ Fc,
    const int*   __restrict__ Iv,
    unsigned short* __restrict__ x16,
    i32x4*          __restrict__ quad,
    f32x4*          __restrict__ wrec)
{
    const int bid = blockIdx.x;
    if (bid < CONV_BLOCKS) {
        const size_t i = ((size_t)bid * 256 + threadIdx.x) * 8;
        const f32x4 a = *(const f32x4*)(xf + i);
        const f32x4 b = *(const f32x4*)(xf + i + 4);
        u16x8 o;
        o.s0 = f32_to_bf16(a.x); o.s1 = f32_to_bf16(a.y);
        o.s2 = f32_to_bf16(a.z); o.s3 = f32_to_bf16(a.w);
        o.s4 = f32_to_bf16(b.x); o.s5 = f32_to_bf16(b.y);
        o.s6 = f32_to_bf16(b.z); o.s7 = f32_to_bf16(b.w);
        *(u16x8*)(x16 + i) = o;
    } else if (bid < CONV_BLOCKS + IDX_BLOCKS) {
        const int e = (bid - CONV_BLOCKS) * 256 + threadIdx.x;
        if (e < N_E) {
            const int s   = xg[e];
            const int fid = Iv[s];
            i32x4 q;
            q.x = Fc[fid * 3 + 0];
            q.y = Fc[fid * 3 + 1];
            q.z = Fc[fid * 3 + 2];
            q.w = s;
            quad[e] = q;
        }
    } else {
        const int i = (bid - CONV_BLOCKS - IDX_BLOCKS) * 256 + threadIdx.x;
        if (i < N_E * BATCH) {
            const int e = i >> 2;
            const int b = i & 3;
            const int s = xg[e];
            const float* p = Bw + ((size_t)b * N_SAMP + s) * 3;
            f32x4 w;
            w.x = p[0]; w.y = p[1]; w.z = p[2]; w.w = 0.0f;
            wrec[i] = w;
        }
    }
}

// ---------------------------------------------------------------------------
// Main: one 16-lane group per (b,v), looping all 8 k (unrolled).
//  - ax row loaded once (registers)       -> 25% fewer feature gathers
//  - w via one 16B broadcast from wrec    -> no random Bw gathers here
//  - stores: 8 consecutive 512B rows per group (4 KB contiguous)
// Grid: 2504 blocks; xcd=L&7 pins each XCD to one batch plane (2 XCDs/plane).
// ---------------------------------------------------------------------------
__global__ __launch_bounds__(256) void disk_features_main(
    const unsigned short* __restrict__ x16,   // [BATCH][N_VERTS][CC] bf16
    const f32x4*          __restrict__ wrec,  // [N_E*BATCH]
    const i32x4*          __restrict__ quad,  // [N_E]
    float*                __restrict__ out)   // [BATCH][N_VERTS][CUT_NUM][CC]
{
    const int L    = blockIdx.x;
    const int xcd  = L & (NXCD - 1);
    const int b    = xcd >> 1;            // 0..3
    const int half = xcd & 1;
    const int idx  = L >> 3;              // 0..312
    const int chunk = idx + half * 313;   // 16-vertex chunk within the plane
    if (chunk >= 625) return;             // 4 guard blocks idle

    const int t    = threadIdx.x;
    const int g    = t >> 4;              // 0..15: which v in the chunk
    const int lane = t & 15;
    const int c0   = lane * 8;            // 8 bf16 channels per lane
    const int v    = chunk * 16 + g;

    const unsigned short* xb = x16 + (size_t)b * N_VERTS * CC;

    const u16x8 axv = *(const u16x8*)(xb + (size_t)v * CC + c0);
    float fx[8];
    #pragma unroll
    for (int j = 0; j < 8; ++j) fx[j] = bf16_to_f32(axv[j]);

    const int e0 = v * CUT_NUM;
    float* dstv = out + ((size_t)b * N_VERTS + v) * CUT_NUM * CC + c0;

    #pragma unroll
    for (int k = 0; k < CUT_NUM; ++k) {
        const i32x4 q = quad[e0 + k];
        const f32x4 w = wrec[(size_t)(e0 + k) * 4 + b];
        const u16x8 a0 = *(const u16x8*)(xb + (size_t)q.x * CC + c0);
        const u16x8 a1 = *(const u16x8*)(xb + (size_t)q.y * CC + c0);
        const u16x8 a2 = *(const u16x8*)(xb + (size_t)q.z * CC + c0);

        f32x4 r0, r1;
        #pragma unroll
        for (int j = 0; j < 4; ++j)
            r0[j] = fmaf(w.x, bf16_to_f32(a0[j]),
                    fmaf(w.y, bf16_to_f32(a1[j]),
                    fmaf(w.z, bf16_to_f32(a2[j]), -fx[j])));
        #pragma unroll
        for (int j = 0; j < 4; ++j)
            r1[j] = fmaf(w.x, bf16_to_f32(a0[j + 4]),
                    fmaf(w.y, bf16_to_f32(a1[j + 4]),
                    fmaf(w.z, bf16_to_f32(a2[j + 4]), -fx[j + 4])));

        float* dst = dstv + (size_t)k * CC;
        __builtin_nontemporal_store(r0, (f32x4*)dst);
        __builtin_nontemporal_store(r1, (f32x4*)(dst + 4));
    }
}

// ---------------------------------------------------------------------------
// Tier-1 fallback: round-11 structure (bf16 table + quad, per-row threads).
// ---------------------------------------------------------------------------
__global__ __launch_bounds__(256) void idx_prep(
    const int* __restrict__ xg,
    const int* __restrict__ Fc,
    const int* __restrict__ Iv,
    i32x4*     __restrict__ quad)
{
    const int e = blockIdx.x * 256 + threadIdx.x;
    if (e >= N_E) return;
    const int s   = xg[e];
    const int fid = Iv[s];
    i32x4 q;
    q.x = Fc[fid * 3 + 0];
    q.y = Fc[fid * 3 + 1];
    q.z = Fc[fid * 3 + 2];
    q.w = s;
    quad[e] = q;
}

__global__ __launch_bounds__(256) void to_bf16_kernel(
    const float* __restrict__ xf, unsigned short* __restrict__ x16)
{
    const size_t i = ((size_t)blockIdx.x * 256 + threadIdx.x) * 8;
    if (i >= (size_t)BATCH * N_VERTS * CC) return;
    const f32x4 a = *(const f32x4*)(xf + i);
    const f32x4 b = *(const f32x4*)(xf + i + 4);
    u16x8 o;
    o.s0 = f32_to_bf16(a.x); o.s1 = f32_to_bf16(a.y);
    o.s2 = f32_to_bf16(a.z); o.s3 = f32_to_bf16(a.w);
    o.s4 = f32_to_bf16(b.x); o.s5 = f32_to_bf16(b.y);
    o.s6 = f32_to_bf16(b.z); o.s7 = f32_to_bf16(b.w);
    *(u16x8*)(x16 + i) = o;
}

__global__ __launch_bounds__(256) void disk_features_r11(
    const unsigned short* __restrict__ x16,
    const float*          __restrict__ Bw,
    const i32x4*          __restrict__ quad,
    float*                __restrict__ out)
{
    const int L    = blockIdx.x;
    const int xcd  = L & (NXCD - 1);
    const int b    = xcd >> 1;
    const int vp   = (L >> 3) + (xcd & 1) * (N_VERTS / 4);
    const int t    = threadIdx.x;
    const int g    = t >> 4;
    const int lane = t & 15;
    const int k    = g & 7;
    const int v    = vp * 2 + (g >> 3);
    const int c0   = lane * 8;

    const i32x4 q = quad[v * CUT_NUM + k];

    const float* bw = Bw + ((size_t)b * N_SAMP + q.w) * 3;
    const float w0 = bw[0];
    const float w1 = bw[1];
    const float w2 = bw[2];

    const unsigned short* xb = x16 + (size_t)b * N_VERTS * CC;
    const u16x8 a0 = *(const u16x8*)(xb + (size_t)q.x * CC + c0);
    const u16x8 a1 = *(const u16x8*)(xb + (size_t)q.y * CC + c0);
    const u16x8 a2 = *(const u16x8*)(xb + (size_t)q.z * CC + c0);
    const u16x8 ax = *(const u16x8*)(xb + (size_t)v   * CC + c0);

    f32x4 r0, r1;
    #pragma unroll
    for (int j = 0; j < 4; ++j)
        r0[j] = fmaf(w0, bf16_to_f32(a0[j]),
                fmaf(w1, bf16_to_f32(a1[j]),
                fmaf(w2, bf16_to_f32(a2[j]), -bf16_to_f32(ax[j]))));
    #pragma unroll
    for (int j = 0; j < 4; ++j)
        r1[j] = fmaf(w0, bf16_to_f32(a0[j + 4]),
                fmaf(w1, bf16_to_f32(a1[j + 4]),
                fmaf(w2, bf16_to_f32(a2[j + 4]), -bf16_to_f32(ax[j + 4]))));

    float* dst = out + ((((size_t)b * N_VERTS + v) * CUT_NUM + k) * CC + c0);
    __builtin_nontemporal_store(r0, (f32x4*)dst);
    __builtin_nontemporal_store(r1, (f32x4*)(dst + 4));
}

__global__ __launch_bounds__(256) void fused_disk_features(
    const float* __restrict__ xf,
    const float* __restrict__ Bw,
    const int*   __restrict__ xg,
    const int*   __restrict__ Fc,
    const int*   __restrict__ Iv,
    float*       __restrict__ out)
{
    const int v    = blockIdx.x;
    const int b    = blockIdx.y;
    const int t    = threadIdx.x;
    const int k    = t >> 5;
    const int lane = t & 31;
    const int c0   = lane * 4;

    const int s   = xg[v * CUT_NUM + k];
    const int fid = Iv[s];
    const int v0  = Fc[fid * 3 + 0];
    const int v1  = Fc[fid * 3 + 1];
    const int v2  = Fc[fid * 3 + 2];

    const float* bw = Bw + ((size_t)b * N_SAMP + s) * 3;
    const float w0 = bw[0];
    const float w1 = bw[1];
    const float w2 = bw[2];

    const float* xb = xf + (size_t)b * N_VERTS * CC;
    const f32x4 f0 = *(const f32x4*)(xb + (size_t)v0 * CC + c0);
    const f32x4 f1 = *(const f32x4*)(xb + (size_t)v1 * CC + c0);
    const f32x4 f2 = *(const f32x4*)(xb + (size_t)v2 * CC + c0);
    const f32x4 fx = *(const f32x4*)(xb + (size_t)v  * CC + c0);

    f32x4 r;
    r.x = fmaf(w0, f0.x, fmaf(w1, f1.x, fmaf(w2, f2.x, -fx.x)));
    r.y = fmaf(w0, f0.y, fmaf(w1, f1.y, fmaf(w2, f2.y, -fx.y)));
    r.z = fmaf(w0, f0.z, fmaf(w1, f1.z, fmaf(w2, f2.z, -fx.z)));
    r.w = fmaf(w0, f0.w, fmaf(w1, f1.w, fmaf(w2, f2.w, -fx.w)));

    f32x4* dst = (f32x4*)(out + ((((size_t)b * N_VERTS + v) * CUT_NUM + k) * CC + c0));
    __builtin_nontemporal_store(r, dst);
}

extern "C" void kernel_launch(void* const* d_in, const int* in_sizes, int n_in,
                              void* d_out, int out_size, void* d_ws, size_t ws_size,
                              hipStream_t stream) {
    const float* xf = (const float*)d_in[0];   // x_features (4,10000,128)
    const float* Bw = (const float*)d_in[1];   // B          (4,80000,3)
    const int*   xg = (const int*)  d_in[2];   // x_graph    (10000,8)
    const int*   Fc = (const int*)  d_in[3];   // F          (20000,3)
    const int*   Iv = (const int*)  d_in[4];   // I          (80000,)
    float*       out = (float*)d_out;          // (4,10000,8,128)

    if (ws_size >= XB16_BYTES + QUAD_BYTES + WREC_BYTES) {
        unsigned short* x16  = (unsigned short*)d_ws;
        i32x4*          quad = (i32x4*)((char*)d_ws + XB16_BYTES);
        f32x4*          wrec = (f32x4*)((char*)d_ws + XB16_BYTES + QUAD_BYTES);
        prep_kernel<<<CONV_BLOCKS + IDX_BLOCKS + WREC_BLOCKS, 256, 0, stream>>>(
            xf, Bw, xg, Fc, Iv, x16, quad, wrec);
        disk_features_main<<<2504, 256, 0, stream>>>(x16, wrec, quad, out);
    } else if (ws_size >= XB16_BYTES + QUAD_BYTES) {
        unsigned short* x16  = (unsigned short*)d_ws;
        i32x4*          quad = (i32x4*)((char*)d_ws + XB16_BYTES);
        to_bf16_kernel<<<CONV_BLOCKS, 256, 0, stream>>>(xf, x16);
        idx_prep<<<IDX_BLOCKS, 256, 0, stream>>>(xg, Fc, Iv, quad);
        disk_features_r11<<<N_VERTS * BATCH / 2, 256, 0, stream>>>(x16, Bw, quad, out);
    } else {
        dim3 grid(N_VERTS, BATCH);
        fused_disk_features<<<grid, 256, 0, stream>>>(xf, Bw, xg, Fc, Iv, out);
    }
}

// Round 14
// 52.443 us; speedup vs baseline: 1.0803x; 1.0803x over previous
//
#include <hip/hip_runtime.h>

// Problem constants (from reference)
#define BATCH   4
#define N_VERTS 10000
#define N_FACES 20000
#define CUT_NUM 8
#define N_SAMP  80000
#define CC      128
#define NXCD    8

typedef float          f32x4 __attribute__((ext_vector_type(4)));
typedef int            i32x4 __attribute__((ext_vector_type(4)));
typedef unsigned short u16x8 __attribute__((ext_vector_type(8)));

#define N_E        (N_VERTS * CUT_NUM)                          // 80000
#define XB16_BYTES ((size_t)BATCH * N_VERTS * CC * 2)           // 10.24 MB
#define QUAD_BYTES ((size_t)N_E * sizeof(i32x4))                // 1.28 MB
#define WREC_BYTES ((size_t)N_E * BATCH * sizeof(f32x4))        // 5.12 MB
#define CONV_BLOCKS 2500   // 2500*256*8 == BATCH*N_VERTS*CC exactly
#define IDX_BLOCKS  313    // ceil(80000/256)
#define WREC_BLOCKS 1250   // 320000/256 exactly

__device__ inline float bf16_to_f32(unsigned short u) {
    return __uint_as_float((unsigned)u << 16);
}

// round-to-nearest-even f32 -> bf16
__device__ inline unsigned short f32_to_bf16(float f) {
    unsigned u = __float_as_uint(f);
    unsigned rounding = 0x7fffu + ((u >> 16) & 1u);
    return (unsigned short)((u + rounding) >> 16);
}

// ---------------------------------------------------------------------------
// Fused prep, 3 segments:
//  [0, CONV)            : x_features f32 -> bf16 table
//  [CONV, CONV+IDX)     : quad[e] = {F[I[s]][0..2], s}, s = xg[e]
//  [CONV+IDX, +WREC)    : wrec[e*4+b] = {Bw[b][xg[e]][0..2], 0} — random Bw
//                         gathers resolved here; main reads one 16B broadcast
// ---------------------------------------------------------------------------
__global__ __launch_bounds__(256) void prep_kernel(
    const float* __restrict__ xf,
    const float* __restrict__ Bw,
    const int*   __restrict__ xg,
    const int*   __restrict__ Fc,
    const int*   __restrict__ Iv,
    unsigned short* __restrict__ x16,
    i32x4*          __restrict__ quad,
    f32x4*          __restrict__ wrec)
{
    const int bid = blockIdx.x;
    if (bid < CONV_BLOCKS) {
        const size_t i = ((size_t)bid * 256 + threadIdx.x) * 8;
        const f32x4 a = *(const f32x4*)(xf + i);
        const f32x4 b = *(const f32x4*)(xf + i + 4);
        u16x8 o;
        o.s0 = f32_to_bf16(a.x); o.s1 = f32_to_bf16(a.y);
        o.s2 = f32_to_bf16(a.z); o.s3 = f32_to_bf16(a.w);
        o.s4 = f32_to_bf16(b.x); o.s5 = f32_to_bf16(b.y);
        o.s6 = f32_to_bf16(b.z); o.s7 = f32_to_bf16(b.w);
        *(u16x8*)(x16 + i) = o;
    } else if (bid < CONV_BLOCKS + IDX_BLOCKS) {
        const int e = (bid - CONV_BLOCKS) * 256 + threadIdx.x;
        if (e < N_E) {
            const int s   = xg[e];
            const int fid = Iv[s];
            i32x4 q;
            q.x = Fc[fid * 3 + 0];
            q.y = Fc[fid * 3 + 1];
            q.z = Fc[fid * 3 + 2];
            q.w = s;
            quad[e] = q;
        }
    } else {
        const int i = (bid - CONV_BLOCKS - IDX_BLOCKS) * 256 + threadIdx.x;
        if (i < N_E * BATCH) {
            const int e = i >> 2;
            const int b = i & 3;
            const int s = xg[e];
            const float* p = Bw + ((size_t)b * N_SAMP + s) * 3;
            f32x4 w;
            w.x = p[0]; w.y = p[1]; w.z = p[2]; w.w = 0.0f;
            wrec[i] = w;
        }
    }
}

// ---------------------------------------------------------------------------
// Main (round-11 structure + wrec): one 16-lane group per output row.
// 20000 blocks = 80000 waves -> deep per-CU queue hides gather latency.
// Per-row VMEM: quad(16B bc) + wrec(16B bc) + 4 gathers(16B) + 2 stores.
// XCD swizzle pins each XCD to one batch plane (2 XCDs per b).
// ---------------------------------------------------------------------------
__global__ __launch_bounds__(256) void disk_features_main(
    const unsigned short* __restrict__ x16,   // [BATCH][N_VERTS][CC] bf16
    const f32x4*          __restrict__ wrec,  // [N_E*BATCH]
    const i32x4*          __restrict__ quad,  // [N_E]
    float*                __restrict__ out)   // [BATCH][N_VERTS][CUT_NUM][CC]
{
    const int L    = blockIdx.x;
    const int xcd  = L & (NXCD - 1);
    const int b    = xcd >> 1;                             // 0..3
    const int vp   = (L >> 3) + (xcd & 1) * (N_VERTS / 4); // 0..4999
    const int t    = threadIdx.x;
    const int g    = t >> 4;          // 0..15 (row group)
    const int lane = t & 15;          // 0..15
    const int k    = g & 7;
    const int v    = vp * 2 + (g >> 3);
    const int c0   = lane * 8;        // 8 bf16 channels per lane

    const int e = v * CUT_NUM + k;
    const i32x4 q = quad[e];
    const f32x4 w = wrec[(size_t)e * 4 + b];

    const unsigned short* xb = x16 + (size_t)b * N_VERTS * CC;
    const u16x8 a0 = *(const u16x8*)(xb + (size_t)q.x * CC + c0);
    const u16x8 a1 = *(const u16x8*)(xb + (size_t)q.y * CC + c0);
    const u16x8 a2 = *(const u16x8*)(xb + (size_t)q.z * CC + c0);
    const u16x8 ax = *(const u16x8*)(xb + (size_t)v   * CC + c0);

    f32x4 r0, r1;
    #pragma unroll
    for (int j = 0; j < 4; ++j)
        r0[j] = fmaf(w.x, bf16_to_f32(a0[j]),
                fmaf(w.y, bf16_to_f32(a1[j]),
                fmaf(w.z, bf16_to_f32(a2[j]), -bf16_to_f32(ax[j]))));
    #pragma unroll
    for (int j = 0; j < 4; ++j)
        r1[j] = fmaf(w.x, bf16_to_f32(a0[j + 4]),
                fmaf(w.y, bf16_to_f32(a1[j + 4]),
                fmaf(w.z, bf16_to_f32(a2[j + 4]), -bf16_to_f32(ax[j + 4]))));

    float* dst = out + ((((size_t)b * N_VERTS + v) * CUT_NUM + k) * CC + c0);
    __builtin_nontemporal_store(r0, (f32x4*)dst);
    __builtin_nontemporal_store(r1, (f32x4*)(dst + 4));
}

// ---------------------------------------------------------------------------
// Tier-1 fallback: exact round-11 path (no wrec).
// ---------------------------------------------------------------------------
__global__ __launch_bounds__(256) void idx_prep(
    const int* __restrict__ xg,
    const int* __restrict__ Fc,
    const int* __restrict__ Iv,
    i32x4*     __restrict__ quad)
{
    const int e = blockIdx.x * 256 + threadIdx.x;
    if (e >= N_E) return;
    const int s   = xg[e];
    const int fid = Iv[s];
    i32x4 q;
    q.x = Fc[fid * 3 + 0];
    q.y = Fc[fid * 3 + 1];
    q.z = Fc[fid * 3 + 2];
    q.w = s;
    quad[e] = q;
}

__global__ __launch_bounds__(256) void to_bf16_kernel(
    const float* __restrict__ xf, unsigned short* __restrict__ x16)
{
    const size_t i = ((size_t)blockIdx.x * 256 + threadIdx.x) * 8;
    if (i >= (size_t)BATCH * N_VERTS * CC) return;
    const f32x4 a = *(const f32x4*)(xf + i);
    const f32x4 b = *(const f32x4*)(xf + i + 4);
    u16x8 o;
    o.s0 = f32_to_bf16(a.x); o.s1 = f32_to_bf16(a.y);
    o.s2 = f32_to_bf16(a.z); o.s3 = f32_to_bf16(a.w);
    o.s4 = f32_to_bf16(b.x); o.s5 = f32_to_bf16(b.y);
    o.s6 = f32_to_bf16(b.z); o.s7 = f32_to_bf16(b.w);
    *(u16x8*)(x16 + i) = o;
}

__global__ __launch_bounds__(256) void disk_features_r11(
    const unsigned short* __restrict__ x16,
    const float*          __restrict__ Bw,
    const i32x4*          __restrict__ quad,
    float*                __restrict__ out)
{
    const int L    = blockIdx.x;
    const int xcd  = L & (NXCD - 1);
    const int b    = xcd >> 1;
    const int vp   = (L >> 3) + (xcd & 1) * (N_VERTS / 4);
    const int t    = threadIdx.x;
    const int g    = t >> 4;
    const int lane = t & 15;
    const int k    = g & 7;
    const int v    = vp * 2 + (g >> 3);
    const int c0   = lane * 8;

    const i32x4 q = quad[v * CUT_NUM + k];

    const float* bw = Bw + ((size_t)b * N_SAMP + q.w) * 3;
    const float w0 = bw[0];
    const float w1 = bw[1];
    const float w2 = bw[2];

    const unsigned short* xb = x16 + (size_t)b * N_VERTS * CC;
    const u16x8 a0 = *(const u16x8*)(xb + (size_t)q.x * CC + c0);
    const u16x8 a1 = *(const u16x8*)(xb + (size_t)q.y * CC + c0);
    const u16x8 a2 = *(const u16x8*)(xb + (size_t)q.z * CC + c0);
    const u16x8 ax = *(const u16x8*)(xb + (size_t)v   * CC + c0);

    f32x4 r0, r1;
    #pragma unroll
    for (int j = 0; j < 4; ++j)
        r0[j] = fmaf(w0, bf16_to_f32(a0[j]),
                fmaf(w1, bf16_to_f32(a1[j]),
                fmaf(w2, bf16_to_f32(a2[j]), -bf16_to_f32(ax[j]))));
    #pragma unroll
    for (int j = 0; j < 4; ++j)
        r1[j] = fmaf(w0, bf16_to_f32(a0[j + 4]),
                fmaf(w1, bf16_to_f32(a1[j + 4]),
                fmaf(w2, bf16_to_f32(a2[j + 4]), -bf16_to_f32(ax[j + 4]))));

    float* dst = out + ((((size_t)b * N_VERTS + v) * CUT_NUM + k) * CC + c0);
    __builtin_nontemporal_store(r0, (f32x4*)dst);
    __builtin_nontemporal_store(r1, (f32x4*)(dst + 4));
}

__global__ __launch_bounds__(256) void fused_disk_features(
    const float* __restrict__ xf,
    const float* __restrict__ Bw,
    const int*   __restrict__ xg,
    const int*   __restrict__ Fc,
    const int*   __restrict__ Iv,
    float*       __restrict__ out)
{
    const int v    = blockIdx.x;
    const int b    = blockIdx.y;
    const int t    = threadIdx.x;
    const int k    = t >> 5;
    const int lane = t & 31;
    const int c0   = lane * 4;

    const int s   = xg[v * CUT_NUM + k];
    const int fid = Iv[s];
    const int v0  = Fc[fid * 3 + 0];
    const int v1  = Fc[fid * 3 + 1];
    const int v2  = Fc[fid * 3 + 2];

    const float* bw = Bw + ((size_t)b * N_SAMP + s) * 3;
    const float w0 = bw[0];
    const float w1 = bw[1];
    const float w2 = bw[2];

    const float* xb = xf + (size_t)b * N_VERTS * CC;
    const f32x4 f0 = *(const f32x4*)(xb + (size_t)v0 * CC + c0);
    const f32x4 f1 = *(const f32x4*)(xb + (size_t)v1 * CC + c0);
    const f32x4 f2 = *(const f32x4*)(xb + (size_t)v2 * CC + c0);
    const f32x4 fx = *(const f32x4*)(xb + (size_t)v  * CC + c0);

    f32x4 r;
    r.x = fmaf(w0, f0.x, fmaf(w1, f1.x, fmaf(w2, f2.x, -fx.x)));
    r.y = fmaf(w0, f0.y, fmaf(w1, f1.y, fmaf(w2, f2.y, -fx.y)));
    r.z = fmaf(w0, f0.z, fmaf(w1, f1.z, fmaf(w2, f2.z, -fx.z)));
    r.w = fmaf(w0, f0.w, fmaf(w1, f1.w, fmaf(w2, f2.w, -fx.w)));

    f32x4* dst = (f32x4*)(out + ((((size_t)b * N_VERTS + v) * CUT_NUM + k) * CC + c0));
    __builtin_nontemporal_store(r, dst);
}

extern "C" void kernel_launch(void* const* d_in, const int* in_sizes, int n_in,
                              void* d_out, int out_size, void* d_ws, size_t ws_size,
                              hipStream_t stream) {
    const float* xf = (const float*)d_in[0];   // x_features (4,10000,128)
    const float* Bw = (const float*)d_in[1];   // B          (4,80000,3)
    const int*   xg = (const int*)  d_in[2];   // x_graph    (10000,8)
    const int*   Fc = (const int*)  d_in[3];   // F          (20000,3)
    const int*   Iv = (const int*)  d_in[4];   // I          (80000,)
    float*       out = (float*)d_out;          // (4,10000,8,128)

    if (ws_size >= XB16_BYTES + QUAD_BYTES + WREC_BYTES) {
        unsigned short* x16  = (unsigned short*)d_ws;
        i32x4*          quad = (i32x4*)((char*)d_ws + XB16_BYTES);
        f32x4*          wrec = (f32x4*)((char*)d_ws + XB16_BYTES + QUAD_BYTES);
        prep_kernel<<<CONV_BLOCKS + IDX_BLOCKS + WREC_BLOCKS, 256, 0, stream>>>(
            xf, Bw, xg, Fc, Iv, x16, quad, wrec);
        disk_features_main<<<N_VERTS * BATCH / 2, 256, 0, stream>>>(x16, wrec, quad, out);
    } else if (ws_size >= XB16_BYTES + QUAD_BYTES) {
        unsigned short* x16  = (unsigned short*)d_ws;
        i32x4*          quad = (i32x4*)((char*)d_ws + XB16_BYTES);
        to_bf16_kernel<<<CONV_BLOCKS, 256, 0, stream>>>(xf, x16);
        idx_prep<<<IDX_BLOCKS, 256, 0, stream>>>(xg, Fc, Iv, quad);
        disk_features_r11<<<N_VERTS * BATCH / 2, 256, 0, stream>>>(x16, Bw, quad, out);
    } else {
        dim3 grid(N_VERTS, BATCH);
        fused_disk_features<<<grid, 256, 0, stream>>>(xf, Bw, xg, Fc, Iv, out);
    }
}

// Round 16
// 47.351 us; speedup vs baseline: 1.1964x; 1.1075x over previous
//
#include <hip/hip_runtime.h>

// Problem constants (from reference)
#define BATCH   4
#define N_VERTS 10000
#define N_FACES 20000
#define CUT_NUM 8
#define N_SAMP  80000
#define CC      128
#define NXCD    8

typedef float          f32x4 __attribute__((ext_vector_type(4)));
typedef int            i32x4 __attribute__((ext_vector_type(4)));
typedef unsigned short u16x4 __attribute__((ext_vector_type(4)));
typedef unsigned short u16x8 __attribute__((ext_vector_type(8)));

#define XB16_BYTES ((size_t)BATCH * N_VERTS * CC * 2)          // 10.24 MB
#define QUAD_BYTES ((size_t)N_VERTS * CUT_NUM * sizeof(i32x4)) // 1.28 MB
#define CONV_BLOCKS 2500   // 2500*256*8 == BATCH*N_VERTS*CC exactly
#define IDX_BLOCKS  313    // ceil(80000/256)

__device__ inline float bf16_to_f32(unsigned short u) {
    return __uint_as_float((unsigned)u << 16);
}

// round-to-nearest-even f32 -> bf16
__device__ inline unsigned short f32_to_bf16(float f) {
    unsigned u = __float_as_uint(f);
    unsigned rounding = 0x7fffu + ((u >> 16) & 1u);
    return (unsigned short)((u + rounding) >> 16);
}

// ---------------------------------------------------------------------------
// Fused prep: blocks [0,CONV_BLOCKS) convert x_features f32->bf16;
// blocks [CONV_BLOCKS, CONV_BLOCKS+IDX_BLOCKS) resolve the index chain:
//   quad[e] = { F[I[s]][0], F[I[s]][1], F[I[s]][2], s },  s = xg[e]
// ---------------------------------------------------------------------------
__global__ __launch_bounds__(256) void prep_kernel(
    const float* __restrict__ xf,
    const int*   __restrict__ xg,
    const int*   __restrict__ Fc,
    const int*   __restrict__ Iv,
    unsigned short* __restrict__ x16,
    i32x4*          __restrict__ quad)
{
    const int bid = blockIdx.x;
    if (bid < CONV_BLOCKS) {
        const size_t i = ((size_t)bid * 256 + threadIdx.x) * 8;
        const f32x4 a = *(const f32x4*)(xf + i);
        const f32x4 b = *(const f32x4*)(xf + i + 4);
        u16x8 o;
        o.s0 = f32_to_bf16(a.x); o.s1 = f32_to_bf16(a.y);
        o.s2 = f32_to_bf16(a.z); o.s3 = f32_to_bf16(a.w);
        o.s4 = f32_to_bf16(b.x); o.s5 = f32_to_bf16(b.y);
        o.s6 = f32_to_bf16(b.z); o.s7 = f32_to_bf16(b.w);
        *(u16x8*)(x16 + i) = o;
    } else {
        const int e = (bid - CONV_BLOCKS) * 256 + threadIdx.x;
        if (e < N_VERTS * CUT_NUM) {
            const int s   = xg[e];
            const int fid = Iv[s];
            i32x4 q;
            q.x = Fc[fid * 3 + 0];
            q.y = Fc[fid * 3 + 1];
            q.z = Fc[fid * 3 + 2];
            q.w = s;
            quad[e] = q;
        }
    }
}

// ---------------------------------------------------------------------------
// Main: 20000 blocks (2 vertices each), XCD-swizzled so each XCD handles one
// batch plane (2 XCDs per b). 16 lanes per output row, 16B/lane bf16 gathers.
//   xcd = L & 7 ; b = xcd >> 1 ; vp = (L>>3) + (xcd&1)*2500 ; v = vp*2 + (g>>3)
// Deep TLP (80000 waves) hides gather latency; per-row work is minimal.
// ---------------------------------------------------------------------------
__global__ __launch_bounds__(256) void disk_features_main(
    const unsigned short* __restrict__ x16,  // [BATCH][N_VERTS][CC] bf16
    const float*          __restrict__ Bw,   // [BATCH][N_SAMP][3]
    const i32x4*          __restrict__ quad, // [N_VERTS*CUT_NUM]
    float*                __restrict__ out)  // [BATCH][N_VERTS][CUT_NUM][CC]
{
    const int L    = blockIdx.x;
    const int xcd  = L & (NXCD - 1);
    const int b    = xcd >> 1;                             // 0..3
    const int vp   = (L >> 3) + (xcd & 1) * (N_VERTS / 4); // 0..4999
    const int t    = threadIdx.x;
    const int g    = t >> 4;          // 0..15 (row group)
    const int lane = t & 15;          // 0..15
    const int k    = g & 7;
    const int v    = vp * 2 + (g >> 3);
    const int c0   = lane * 8;        // 8 bf16 channels per lane

    const i32x4 q = quad[v * CUT_NUM + k];

    const float* bw = Bw + ((size_t)b * N_SAMP + q.w) * 3;
    const float w0 = bw[0];
    const float w1 = bw[1];
    const float w2 = bw[2];

    const unsigned short* xb = x16 + (size_t)b * N_VERTS * CC;
    const u16x8 a0 = *(const u16x8*)(xb + (size_t)q.x * CC + c0);
    const u16x8 a1 = *(const u16x8*)(xb + (size_t)q.y * CC + c0);
    const u16x8 a2 = *(const u16x8*)(xb + (size_t)q.z * CC + c0);
    const u16x8 ax = *(const u16x8*)(xb + (size_t)v   * CC + c0);

    f32x4 r0, r1;
    #pragma unroll
    for (int j = 0; j < 4; ++j) {
        const float f0 = bf16_to_f32(a0[j]);
        const float f1 = bf16_to_f32(a1[j]);
        const float f2 = bf16_to_f32(a2[j]);
        const float fx = bf16_to_f32(ax[j]);
        r0[j] = fmaf(w0, f0, fmaf(w1, f1, fmaf(w2, f2, -fx)));
    }
    #pragma unroll
    for (int j = 0; j < 4; ++j) {
        const float f0 = bf16_to_f32(a0[j + 4]);
        const float f1 = bf16_to_f32(a1[j + 4]);
        const float f2 = bf16_to_f32(a2[j + 4]);
        const float fx = bf16_to_f32(ax[j + 4]);
        r1[j] = fmaf(w0, f0, fmaf(w1, f1, fmaf(w2, f2, -fx)));
    }

    float* dst = out + ((((size_t)b * N_VERTS + v) * CUT_NUM + k) * CC + c0);
    __builtin_nontemporal_store(r0, (f32x4*)dst);
    __builtin_nontemporal_store(r1, (f32x4*)(dst + 4));
}

// ---------------------------------------------------------------------------
// Fallback paths (smaller ws).
// ---------------------------------------------------------------------------
__global__ __launch_bounds__(256) void idx_prep(
    const int* __restrict__ xg,
    const int* __restrict__ Fc,
    const int* __restrict__ Iv,
    i32x4*     __restrict__ quad)
{
    const int e = blockIdx.x * 256 + threadIdx.x;
    if (e >= N_VERTS * CUT_NUM) return;
    const int s   = xg[e];
    const int fid = Iv[s];
    i32x4 q;
    q.x = Fc[fid * 3 + 0];
    q.y = Fc[fid * 3 + 1];
    q.z = Fc[fid * 3 + 2];
    q.w = s;
    quad[e] = q;
}

__global__ __launch_bounds__(256) void disk_features_f32(
    const float* __restrict__ xf,
    const float* __restrict__ Bw,
    const i32x4* __restrict__ quad,
    float*       __restrict__ out)
{
    const int v    = blockIdx.x;
    const int b    = blockIdx.y;
    const int t    = threadIdx.x;
    const int k    = t >> 5;
    const int lane = t & 31;
    const int c0   = lane * 4;

    const i32x4 q = quad[v * CUT_NUM + k];

    const float* bw = Bw + ((size_t)b * N_SAMP + q.w) * 3;
    const float w0 = bw[0];
    const float w1 = bw[1];
    const float w2 = bw[2];

    const float* xb = xf + (size_t)b * N_VERTS * CC;
    const f32x4 f0 = *(const f32x4*)(xb + (size_t)q.x * CC + c0);
    const f32x4 f1 = *(const f32x4*)(xb + (size_t)q.y * CC + c0);
    const f32x4 f2 = *(const f32x4*)(xb + (size_t)q.z * CC + c0);
    const f32x4 fx = *(const f32x4*)(xb + (size_t)v   * CC + c0);

    f32x4 r;
    r.x = fmaf(w0, f0.x, fmaf(w1, f1.x, fmaf(w2, f2.x, -fx.x)));
    r.y = fmaf(w0, f0.y, fmaf(w1, f1.y, fmaf(w2, f2.y, -fx.y)));
    r.z = fmaf(w0, f0.z, fmaf(w1, f1.z, fmaf(w2, f2.z, -fx.z)));
    r.w = fmaf(w0, f0.w, fmaf(w1, f1.w, fmaf(w2, f2.w, -fx.w)));

    f32x4* dst = (f32x4*)(out + ((((size_t)b * N_VERTS + v) * CUT_NUM + k) * CC + c0));
    __builtin_nontemporal_store(r, dst);
}

__global__ __launch_bounds__(256) void fused_disk_features(
    const float* __restrict__ xf,
    const float* __restrict__ Bw,
    const int*   __restrict__ xg,
    const int*   __restrict__ Fc,
    const int*   __restrict__ Iv,
    float*       __restrict__ out)
{
    const int v    = blockIdx.x;
    const int b    = blockIdx.y;
    const int t    = threadIdx.x;
    const int k    = t >> 5;
    const int lane = t & 31;
    const int c0   = lane * 4;

    const int s   = xg[v * CUT_NUM + k];
    const int fid = Iv[s];
    const int v0  = Fc[fid * 3 + 0];
    const int v1  = Fc[fid * 3 + 1];
    const int v2  = Fc[fid * 3 + 2];

    const float* bw = Bw + ((size_t)b * N_SAMP + s) * 3;
    const float w0 = bw[0];
    const float w1 = bw[1];
    const float w2 = bw[2];

    const float* xb = xf + (size_t)b * N_VERTS * CC;
    const f32x4 f0 = *(const f32x4*)(xb + (size_t)v0 * CC + c0);
    const f32x4 f1 = *(const f32x4*)(xb + (size_t)v1 * CC + c0);
    const f32x4 f2 = *(const f32x4*)(xb + (size_t)v2 * CC + c0);
    const f32x4 fx = *(const f32x4*)(xb + (size_t)v  * CC + c0);

    f32x4 r;
    r.x = fmaf(w0, f0.x, fmaf(w1, f1.x, fmaf(w2, f2.x, -fx.x)));
    r.y = fmaf(w0, f0.y, fmaf(w1, f1.y, fmaf(w2, f2.y, -fx.y)));
    r.z = fmaf(w0, f0.z, fmaf(w1, f1.z, fmaf(w2, f2.z, -fx.z)));
    r.w = fmaf(w0, f0.w, fmaf(w1, f1.w, fmaf(w2, f2.w, -fx.w)));

    f32x4* dst = (f32x4*)(out + ((((size_t)b * N_VERTS + v) * CUT_NUM + k) * CC + c0));
    __builtin_nontemporal_store(r, dst);
}

extern "C" void kernel_launch(void* const* d_in, const int* in_sizes, int n_in,
                              void* d_out, int out_size, void* d_ws, size_t ws_size,
                              hipStream_t stream) {
    const float* xf = (const float*)d_in[0];   // x_features (4,10000,128)
    const float* Bw = (const float*)d_in[1];   // B          (4,80000,3)
    const int*   xg = (const int*)  d_in[2];   // x_graph    (10000,8)
    const int*   Fc = (const int*)  d_in[3];   // F          (20000,3)
    const int*   Iv = (const int*)  d_in[4];   // I          (80000,)
    float*       out = (float*)d_out;          // (4,10000,8,128)

    const int n_e = N_VERTS * CUT_NUM;

    if (ws_size >= XB16_BYTES + QUAD_BYTES) {
        unsigned short* x16  = (unsigned short*)d_ws;
        i32x4*          quad = (i32x4*)((char*)d_ws + XB16_BYTES);
        prep_kernel<<<CONV_BLOCKS + IDX_BLOCKS, 256, 0, stream>>>(xf, xg, Fc, Iv, x16, quad);
        disk_features_main<<<N_VERTS * BATCH / 2, 256, 0, stream>>>(x16, Bw, quad, out);
    } else if (ws_size >= QUAD_BYTES) {
        i32x4* quad = (i32x4*)d_ws;
        idx_prep<<<(n_e + 255) / 256, 256, 0, stream>>>(xg, Fc, Iv, quad);
        dim3 grid(N_VERTS, BATCH);
        disk_features_f32<<<grid, 256, 0, stream>>>(xf, Bw, quad, out);
    } else {
        dim3 grid(N_VERTS, BATCH);
        fused_disk_features<<<grid, 256, 0, stream>>>(xf, Bw, xg, Fc, Iv, out);
    }
}